// Round 17
// baseline (84.051 us; speedup 1.0000x reference)
//
#include <hip/hip_runtime.h>
#include <cstddef>
#include <cstdint>

#define B_ 2
#define T_ 4
#define N_ 1024
#define FIN_ 256
#define H_ 8
#define D_ 128
#define L2E_ 1.4426950408889634f

typedef __attribute__((ext_vector_type(8))) short short8;
typedef __attribute__((ext_vector_type(4))) float f32x4;
typedef __attribute__((ext_vector_type(2))) float f32x2;

#define MFMA16(A, B, C) __builtin_amdgcn_mfma_f32_16x16x32_bf16((A), (B), (C), 0, 0, 0)

__device__ __forceinline__ unsigned short f2bf(float f) {
    uint32_t u = __float_as_uint(f);
    uint32_t r = (u + 0x7fffu + ((u >> 16) & 1u)) >> 16;   // RNE
    return (unsigned short)r;
}

__device__ __forceinline__ uint32_t cvt_pk_bf16(float lo, float hi) {
    uint32_t r;
    asm volatile("v_cvt_pk_bf16_f32 %0, %1, %2" : "=v"(r) : "v"(lo), "v"(hi));
    return r;
}

// raw v_exp_f32 (2^x) — avoids OCML guarded exp2f expansion
__device__ __forceinline__ float fexp2(float x) {
#if __has_builtin(__builtin_amdgcn_exp2f)
    return __builtin_amdgcn_exp2f(x);
#else
    float r;
    asm("v_exp_f32 %0, %1" : "=v"(r) : "v"(x));
    return r;
#endif
}

// async global->LDS, 16B per lane (dest = wave base + lane*16)
__device__ __forceinline__ void load_lds16(const unsigned short* g, unsigned short* l) {
    __builtin_amdgcn_global_load_lds(
        (const __attribute__((address_space(1))) uint32_t*)g,
        (__attribute__((address_space(3))) uint32_t*)l, 16, 0, 0);
}

// ---------------------------------------------------------------------------
// Kernel 0 (prep, tiny): [0,64) W [s][hk] -> Wt_bf [hk][s] bf16;
// [64,80) wa[s][head*2+st] = sum_d W[s][head*128+d]*a[head*256+st*128+d]
// ---------------------------------------------------------------------------
__global__ __launch_bounds__(256) void k_prep(const float* __restrict__ W,
                                              const float* __restrict__ a,
                                              unsigned short* __restrict__ Wt_bf,
                                              float* __restrict__ wa) {
    __shared__ float wl[64][68];
    const int bid = blockIdx.x, tid = threadIdx.x;
    if (bid < 64) {                       // ---- W transpose -> bf16
        const int tb  = bid;
        const int hk0 = (tb >> 2) * 64;
        const int s0  = (tb & 3) * 64;
        {
            const int r  = tid >> 2;
            const int c0 = (tid & 3) * 16;
            #pragma unroll
            for (int k = 0; k < 4; ++k)
                *(float4*)&wl[r][c0 + k * 4] =
                    *(const float4*)(W + (size_t)(s0 + r) * (H_ * D_) + hk0 + c0 + k * 4);
        }
        __syncthreads();
        {
            const int r2 = tid >> 2;
            const int c2 = (tid & 3) * 16;
            unsigned short ob[16];
            #pragma unroll
            for (int k = 0; k < 16; ++k) ob[k] = f2bf(wl[c2 + k][r2]);
            unsigned short* dst = Wt_bf + (size_t)(hk0 + r2) * FIN_ + s0 + c2;
            *(uint4*)(dst)     = *(uint4*)&ob[0];
            *(uint4*)(dst + 8) = *(uint4*)&ob[8];
        }
    } else {                              // ---- wa
        const int o    = (bid - 64) * 256 + tid;
        const int head = o >> 9;
        const int st   = (o >> 8) & 1;
        const int s    = o & 255;
        const float* wr = W + (size_t)s * (H_ * D_) + head * D_;
        const float* ar = a + head * 256 + st * 128;
        float sum = 0.f;
        #pragma unroll
        for (int d = 0; d < 128; d += 4) {
            const float4 wv = *(const float4*)(wr + d);
            const float4 av = *(const float4*)(ar + d);
            sum += wv.x * av.x + wv.y * av.y + wv.z * av.z + wv.w * av.w;
        }
        wa[s * 16 + head * 2 + st] = sum;
    }
}

// ---------------------------------------------------------------------------
// Kernel 1 (merged): [0,1024) LDS 2-phase bf16 MFMA GEMM -> htT[bth][d][n];
// async A-staging split (T14), counted vmcnt(4). [1024,1152) prescaled
// s1/t1 (= proj * L2E). [1152,1664) adjm pair-mask packing.
// ---------------------------------------------------------------------------
__global__ __launch_bounds__(256, 2) void k_gemm_sp(const float* __restrict__ h,
                                                    const unsigned short* __restrict__ Wt_bf,
                                                    const float* __restrict__ wa,
                                                    const int* __restrict__ adj,
                                                    unsigned short* __restrict__ htT,
                                                    float* __restrict__ s1,
                                                    float* __restrict__ t1,
                                                    uint32_t* __restrict__ adjm) {
    __shared__ __align__(16) char smem[24576];
    const int bid = blockIdx.x, tid = threadIdx.x;
    if (bid < 1024) {                     // ---- GEMM
        unsigned short* a_lds = (unsigned short*)smem;            // [2][4096]
        unsigned short* b_lds = (unsigned short*)(smem + 16384);  // [2][2048]
        const int xcd  = bid & 7;
        const int slot = bid >> 3;
        const int gid  = xcd * 8 + (slot >> 4);
        const int bt   = gid >> 3;
        const int n0   = (gid & 7) * 128;
        const int hk0  = (slot & 15) * 64;
        const int w = tid >> 6, lane = tid & 63;
        const int row16 = lane & 15, kgrp = lane >> 4;
        const int kswz = (kgrp ^ ((row16 >> 1) & 3)) * 8;
        const int ar  = tid >> 1;
        const int akh = tid & 1;
        const int asub = ar >> 4, arow = ar & 15;
        const int ax = (arow >> 1) & 3;
        const int aslot0 = ((akh * 2) ^ ax) * 8;
        const int aslot1 = ((akh * 2 + 1) ^ ax) * 8;
        const float* ga = h + ((size_t)bt * N_ + n0 + ar) * FIN_ + akh * 16;
        unsigned short* aw_ = a_lds + asub * 512 + arow * 32;
        const int brow = lane >> 2;
        const int bsb  = (lane & 3) ^ ((lane >> 3) & 3);
        const unsigned short* gb = Wt_bf + (size_t)(hk0 + w * 16 + brow) * FIN_ + bsb * 8;
        unsigned short* bw_ = b_lds + w * 512 + (size_t)lane * 8;

        float4 rf0, rf1, rf2, rf3;    // A-staging register set (1 iter ahead)

#define LOADA(KS) {                                                            \
        const float* g = ga + (KS) * 32;                                       \
        rf0 = *(const float4*)(g);      rf1 = *(const float4*)(g + 4);         \
        rf2 = *(const float4*)(g + 8);  rf3 = *(const float4*)(g + 12); }

#define WRITEA(BUF) {                                                          \
        uint4 o0, o1;                                                          \
        o0.x = cvt_pk_bf16(rf0.x, rf0.y); o0.y = cvt_pk_bf16(rf0.z, rf0.w);    \
        o0.z = cvt_pk_bf16(rf1.x, rf1.y); o0.w = cvt_pk_bf16(rf1.z, rf1.w);    \
        o1.x = cvt_pk_bf16(rf2.x, rf2.y); o1.y = cvt_pk_bf16(rf2.z, rf2.w);    \
        o1.z = cvt_pk_bf16(rf3.x, rf3.y); o1.w = cvt_pk_bf16(rf3.z, rf3.w);    \
        unsigned short* ad = aw_ + (BUF) * 4096;                               \
        *(uint4*)(ad + aslot0) = o0;                                           \
        *(uint4*)(ad + aslot1) = o1; }

#define COMPK(BUF) {                                                           \
        const unsigned short* ab = a_lds + (BUF) * 4096;                       \
        const short8 bfv = *(const short8*)(b_lds + (BUF) * 2048 + w * 512 + row16 * 32 + kswz); \
        _Pragma("unroll")                                                      \
        for (int nt = 0; nt < 8; ++nt) {                                       \
            const short8 afv = *(const short8*)(ab + nt * 512 + row16 * 32 + kswz); \
            acc[nt] = MFMA16(afv, bfv, acc[nt]);                               \
        } }

        f32x4 acc[8];
        #pragma unroll
        for (int nt = 0; nt < 8; ++nt) acc[nt] = (f32x4){0.f, 0.f, 0.f, 0.f};

        LOADA(0)
        WRITEA(0)
        load_lds16(gb, bw_);
        LOADA(1)
        asm volatile("s_waitcnt vmcnt(4) lgkmcnt(0)" ::: "memory");
        __builtin_amdgcn_s_barrier();

        for (int ks = 0; ks < 8; ++ks) {
            const int cur = ks & 1;
            WRITEA(cur ^ 1)                                      // A(ks+1)
            load_lds16(gb + ((ks + 1) & 7) * 32, bw_ + (cur ^ 1) * 2048);
            LOADA((ks + 2) & 7)
            COMPK(cur)
            asm volatile("s_waitcnt vmcnt(4) lgkmcnt(0)" ::: "memory");
            __builtin_amdgcn_s_barrier();
        }
#undef LOADA
#undef WRITEA
#undef COMPK
        const int hk   = hk0 + w * 16 + row16;
        const int head = hk >> 7;
        const int d    = hk & 127;
        unsigned short* ob = htT + ((size_t)(bt * H_ + head) * D_ + d) * N_;
        #pragma unroll
        for (int nt = 0; nt < 8; ++nt) {
            ushort4 v;
            v.x = f2bf(acc[nt][0]); v.y = f2bf(acc[nt][1]);
            v.z = f2bf(acc[nt][2]); v.w = f2bf(acc[nt][3]);
            *(ushort4*)(ob + n0 + nt * 16 + kgrp * 4) = v;
        }
    } else if (bid < 1152) {              // ---- prescaled src/tgt projections
        float (*was)[16] = (float(*)[16])smem;
        {
            const int f = tid * 16;
            #pragma unroll
            for (int k = 0; k < 4; ++k)
                *(float4*)&was[f >> 4][k * 4] = *(const float4*)(wa + f + k * 4);
        }
        __syncthreads();
        const int r = tid >> 2, q = tid & 3;
        const int R = (bid - 1024) * 64 + r;
        const float* hrow = h + (size_t)R * FIN_ + q * 64;
        float acc[16];
        #pragma unroll
        for (int o = 0; o < 16; ++o) acc[o] = 0.f;
        for (int k = 0; k < 64; k += 4) {
            const float4 hv = *(const float4*)(hrow + k);
            const int s = q * 64 + k;
            #pragma unroll
            for (int kk = 0; kk < 4; ++kk) {
                const float hs = (kk == 0) ? hv.x : (kk == 1) ? hv.y : (kk == 2) ? hv.z : hv.w;
                #pragma unroll
                for (int o = 0; o < 16; ++o) acc[o] += hs * was[s + kk][o];
            }
        }
        #pragma unroll
        for (int o = 0; o < 16; ++o) {
            acc[o] += __shfl_xor(acc[o], 1);
            acc[o] += __shfl_xor(acc[o], 2);
        }
        const int bt = R >> 10, n = R & 1023;
        #pragma unroll
        for (int k = 0; k < 4; ++k) {
            const int o = q * 4 + k;
            const int head = o >> 1;
            const size_t idx = ((size_t)(bt * H_ + head)) * N_ + n;
            const float v = acc[o] * L2E_;
            if (o & 1) t1[idx] = v;
            else       s1[idx] = v;
        }
    } else {                              // ---- adjm pair-mask packing
        const int w0 = ((bid - 1152) * 256 + tid) * 4;
        const int4 p0 = *(const int4*)(adj + (size_t)w0 * 2);
        const int4 p1 = *(const int4*)(adj + (size_t)w0 * 2 + 4);
        uint4 m;
        m.x = (p0.x > 0 ? 0xFFFFu : 0u) | (p0.y > 0 ? 0xFFFF0000u : 0u);
        m.y = (p0.z > 0 ? 0xFFFFu : 0u) | (p0.w > 0 ? 0xFFFF0000u : 0u);
        m.z = (p1.x > 0 ? 0xFFFFu : 0u) | (p1.y > 0 ? 0xFFFF0000u : 0u);
        m.w = (p1.z > 0 ? 0xFFFFu : 0u) | (p1.w > 0 ? 0xFFFF0000u : 0u);
        *(uint4*)(adjm + w0) = m;
    }
}

// score-operand register set (statically addressed struct; rule-20 safe)
struct SC {
    float4 a1l, a1h;      // t1 (prescaled tgt*L2E) for 8 j
    uint4  m4A;           // pair-masks for the wave's 16 rows' lane-row (8 j)
};

// ---------------------------------------------------------------------------
// Kernel 2: fused mask+softmax+PV via MFMA — HIGH-TLP variant.
// grid 1024 (XCD-swizzled: 4 th x 32 i-tiles of 32 rows per XCD) = exactly
// 4 blocks/CU; block 256 = 4 waves; wave = 16 i-rows (single MFMA chain)
// x one b (b=w&1, half=w>>1). 4096 waves = 4 waves/SIMD (2x R13's TLP).
// LDS 32KB: double-buffered [2b][128d][32j] bf16 (16KB/tile), cooperatively
// staged (R9 mapping: wave w stages quarter w, 4 x global_load_lds),
// XOR-swizzled (pre-swizzled source + swizzled ds_read).
// Loop (32 iters): vmcnt(3) (= 3 sc loads newer than awaited stage(t)) ->
// raw s_barrier -> STAGE(t+1) -> SUBP: lean scores (e2=0.2*e1, pair-mask
// AND, raw v_exp), reload sc, 8 ds_read_b128, 8 MFMA + ones-column denom.
// Epilogue: cross-b mean via 16KB LDS comb (2 barriers).
// ---------------------------------------------------------------------------
__global__ __launch_bounds__(256, 2) void k_attn(const unsigned short* __restrict__ htT,
                                                 const float* __restrict__ s1,
                                                 const float* __restrict__ t1,
                                                 const uint32_t* __restrict__ adjm,
                                                 float* __restrict__ out) {
    __shared__ __align__(16) char smem[32768];
    unsigned short* stg = (unsigned short*)smem;   // 2 bufs x 8192 shorts
    const int xcd  = blockIdx.x & 7;
    const int slot = blockIdx.x >> 3;              // 0..127
    const int th   = xcd * 4 + (slot >> 5);        // 0..31
    const int i0   = (slot & 31) * 32;
    const int tid = threadIdx.x;
    const int w = tid >> 6, lane = tid & 63;
    const int b = w & 1, half = w >> 1;
    const int row16 = lane & 15, kgrp = lane >> 4, jrel = kgrp * 8;
    const int kswz = (kgrp ^ ((row16 >> 1) & 3)) * 8;
    const int bth = b * (T_ * H_) + th;
    const int iA  = i0 + half * 16 + row16;
    const float s1A = s1[(size_t)bth * N_ + iA];
    const f32x2 s1A2 = {s1A, s1A};
    const f32x2 c02  = {0.2f, 0.2f};
    const float* t1b = t1 + (size_t)bth * N_;
    const uint32_t* amA = adjm + (size_t)iA * (N_ / 2);

    // cooperative staging (R9 mapping): wave w stages quarter w of the
    // [2b][128][32] tile: staged b = w>>1, d-rows (w&1)*64 + (lane>>2) + 16p
    const int sb  = w >> 1;
    const int sd0 = (w & 1) * 64 + (lane >> 2);
    const int sj  = ((lane & 3) ^ ((lane >> 3) & 3)) * 8;   // pre-swizzled j
    const unsigned short* gstg = htT + ((size_t)(sb * (T_ * H_) + th) * D_ + sd0) * N_ + sj;
    unsigned short* lstg = stg + (size_t)w * 2048 + (size_t)lane * 8;

#define STAGE(BUF, T32) {                                        \
        const unsigned short* gs = gstg + (size_t)(T32) * 32;    \
        unsigned short* ls = lstg + (BUF) * 8192;                \
        load_lds16(gs,           ls);                            \
        load_lds16(gs + 16 * N_, ls + 512);                      \
        load_lds16(gs + 32 * N_, ls + 1024);                     \
        load_lds16(gs + 48 * N_, ls + 1536); }

#define LOADSC(S, T32) {                                         \
        S.a1l = *(const float4*)(t1b + (T32) * 32 + jrel);       \
        S.a1h = *(const float4*)(t1b + (T32) * 32 + jrel + 4);   \
        S.m4A = *(const uint4*)(amA + (T32) * 16 + kgrp * 4); }

    f32x4 acc[8];
    #pragma unroll
    for (int nt = 0; nt < 8; ++nt) acc[nt] = (f32x4){0.f, 0.f, 0.f, 0.f};
    f32x4 dacc = (f32x4){0.f, 0.f, 0.f, 0.f};
    short8 ones8;
    {
        const short ov = (row16 == 0) ? (short)0x3F80 : (short)0;
        #pragma unroll
        for (int e = 0; e < 8; ++e) ones8[e] = ov;
    }
    const unsigned short* rdbase = stg + b * 4096 + row16 * 32 + kswz;

    SC sc;

    // sub-phase: consume sc -> af frag (lean single-chain); reload sc;
    // 8 ds_read_b128; 8 MFMA + ones-column denominator MFMA
#define SUBP(BUFIDX, TNEXT)                                                    \
    {                                                                          \
        const f32x2 tq[4] = {{sc.a1l.x, sc.a1l.y}, {sc.a1l.z, sc.a1l.w},       \
                             {sc.a1h.x, sc.a1h.y}, {sc.a1h.z, sc.a1h.w}};      \
        const uint32_t mAw[4] = {sc.m4A.x, sc.m4A.y, sc.m4A.z, sc.m4A.w};      \
        short8 af;                                                             \
        _Pragma("unroll")                                                      \
        for (int p = 0; p < 4; ++p) {                                          \
            const f32x2 eA  = s1A2 + tq[p];                                    \
            const f32x2 eA2 = eA * c02;                                        \
            const float wA0 = fexp2(fmaxf(eA[0], eA2[0]));                     \
            const float wA1 = fexp2(fmaxf(eA[1], eA2[1]));                     \
            ((uint32_t*)&af)[p] = cvt_pk_bf16(wA0, wA1) & mAw[p];              \
        }                                                                      \
        LOADSC(sc, (TNEXT))                                                    \
        const unsigned short* rb = rdbase + (BUFIDX) * 8192;                   \
        short8 bfr[8];                                                         \
        _Pragma("unroll")                                                      \
        for (int nt = 0; nt < 8; ++nt) bfr[nt] = *(const short8*)(rb + nt * 512); \
        _Pragma("unroll")                                                      \
        for (int nt = 0; nt < 8; ++nt) acc[nt] = MFMA16(af, bfr[nt], acc[nt]); \
        dacc = MFMA16(af, ones8, dacc);                                        \
    }

    STAGE(0, 0)
    LOADSC(sc, 0)

    for (int t = 0; t < 32; ++t) {
        // wait stage(t); newer in flight: sc(t) 3 loads
        asm volatile("s_waitcnt vmcnt(3)" ::: "memory");
        __builtin_amdgcn_s_barrier();
        asm volatile("" ::: "memory");
        STAGE((t + 1) & 1, (t + 1) & 31)
        SUBP(t & 1, (t + 1) & 31)
    }
#undef SUBP
#undef LOADSC
#undef STAGE

    // inverse denominators: D[row=kgrp*4+r][0] lives at lane kgrp*16, reg r
    float iv[4];
    #pragma unroll
    for (int r = 0; r < 4; ++r)
        iv[r] = __shfl(1.0f / dacc[r], kgrp * 16);

    // cross-b mean via LDS comb (32 rows x 128 f32 = 16KB)
    __syncthreads();   // drain wraparound stage before LDS reuse
    float* comb = (float*)smem;
    if (b == 1) {
        #pragma unroll
        for (int nt = 0; nt < 8; ++nt)
            #pragma unroll
            for (int r = 0; r < 4; ++r) {
                const int il = half * 16 + kgrp * 4 + r;
                const int d  = nt * 16 + row16;
                comb[il * 128 + d] = acc[nt][r] * iv[r];
            }
    }
    __syncthreads();
    if (b == 0) {
        #pragma unroll
        for (int nt = 0; nt < 8; ++nt)
            #pragma unroll
            for (int r = 0; r < 4; ++r) {
                const int il = half * 16 + kgrp * 4 + r;
                const int d  = nt * 16 + row16;
                out[((size_t)th * N_ + i0 + il) * D_ + d] =
                    0.5f * (acc[nt][r] * iv[r] + comb[il * 128 + d]);
            }
    }
}

extern "C" void kernel_launch(void* const* d_in, const int* in_sizes, int n_in,
                              void* d_out, int out_size, void* d_ws, size_t ws_size,
                              hipStream_t stream) {
    const float* h   = (const float*)d_in[0];
    const int*   adj = (const int*)d_in[1];
    const float* W   = (const float*)d_in[2];
    const float* a   = (const float*)d_in[3];
    float* out = (float*)d_out;

    // ws: htT 16.78MB | s1,t1 2x256KB | adjm 2MB | Wt_bf 512KB | wa 16KB
    char* p = (char*)d_ws;
    unsigned short* htT = (unsigned short*)p;  p += (size_t)B_ * T_ * H_ * D_ * N_ * 2;
    float* s1 = (float*)p;                     p += (size_t)B_ * T_ * H_ * N_ * 4;
    float* t1 = (float*)p;                     p += (size_t)B_ * T_ * H_ * N_ * 4;
    uint32_t* adjm = (uint32_t*)p;             p += (size_t)N_ * N_ / 2 * 4;
    unsigned short* Wt_bf = (unsigned short*)p;p += (size_t)(H_ * D_) * FIN_ * 2;
    float* wa = (float*)p;

    k_prep<<<dim3(80), dim3(256), 0, stream>>>(W, a, Wt_bf, wa);
    k_gemm_sp<<<dim3(1664), dim3(256), 0, stream>>>(h, Wt_bf, wa, adj, htT, s1, t1, adjm);
    k_attn<<<dim3(1024), dim3(256), 0, stream>>>(htT, s1, t1, adjm, out);
}

// Round 18
// 71.054 us; speedup vs baseline: 1.1829x; 1.1829x over previous
//
#include <hip/hip_runtime.h>
#include <cstddef>
#include <cstdint>

#define B_ 2
#define T_ 4
#define N_ 1024
#define FIN_ 256
#define H_ 8
#define D_ 128
#define L2E_ 1.4426950408889634f

typedef __attribute__((ext_vector_type(8))) short short8;
typedef __attribute__((ext_vector_type(4))) float f32x4;
typedef __attribute__((ext_vector_type(2))) float f32x2;

#define MFMA16(A, B, C) __builtin_amdgcn_mfma_f32_16x16x32_bf16((A), (B), (C), 0, 0, 0)

__device__ __forceinline__ unsigned short f2bf(float f) {
    uint32_t u = __float_as_uint(f);
    uint32_t r = (u + 0x7fffu + ((u >> 16) & 1u)) >> 16;   // RNE
    return (unsigned short)r;
}

__device__ __forceinline__ uint32_t cvt_pk_bf16(float lo, float hi) {
    uint32_t r;
    asm volatile("v_cvt_pk_bf16_f32 %0, %1, %2" : "=v"(r) : "v"(lo), "v"(hi));
    return r;
}

// raw v_exp_f32 (2^x) — avoids OCML guarded exp2f expansion
__device__ __forceinline__ float fexp2(float x) {
#if __has_builtin(__builtin_amdgcn_exp2f)
    return __builtin_amdgcn_exp2f(x);
#else
    float r;
    asm("v_exp_f32 %0, %1" : "=v"(r) : "v"(x));
    return r;
#endif
}

// async global->LDS, 16B per lane (dest = wave base + lane*16)
__device__ __forceinline__ void load_lds16(const unsigned short* g, unsigned short* l) {
    __builtin_amdgcn_global_load_lds(
        (const __attribute__((address_space(1))) uint32_t*)g,
        (__attribute__((address_space(3))) uint32_t*)l, 16, 0, 0);
}

// ---------------------------------------------------------------------------
// Kernel 0 (prep, tiny): [0,64) W [s][hk] -> Wt_bf [hk][s] bf16;
// [64,80) wa[s][head*2+st] = sum_d W[s][head*128+d]*a[head*256+st*128+d]
// ---------------------------------------------------------------------------
__global__ __launch_bounds__(256) void k_prep(const float* __restrict__ W,
                                              const float* __restrict__ a,
                                              unsigned short* __restrict__ Wt_bf,
                                              float* __restrict__ wa) {
    __shared__ float wl[64][68];
    const int bid = blockIdx.x, tid = threadIdx.x;
    if (bid < 64) {                       // ---- W transpose -> bf16
        const int tb  = bid;
        const int hk0 = (tb >> 2) * 64;
        const int s0  = (tb & 3) * 64;
        {
            const int r  = tid >> 2;
            const int c0 = (tid & 3) * 16;
            #pragma unroll
            for (int k = 0; k < 4; ++k)
                *(float4*)&wl[r][c0 + k * 4] =
                    *(const float4*)(W + (size_t)(s0 + r) * (H_ * D_) + hk0 + c0 + k * 4);
        }
        __syncthreads();
        {
            const int r2 = tid >> 2;
            const int c2 = (tid & 3) * 16;
            unsigned short ob[16];
            #pragma unroll
            for (int k = 0; k < 16; ++k) ob[k] = f2bf(wl[c2 + k][r2]);
            unsigned short* dst = Wt_bf + (size_t)(hk0 + r2) * FIN_ + s0 + c2;
            *(uint4*)(dst)     = *(uint4*)&ob[0];
            *(uint4*)(dst + 8) = *(uint4*)&ob[8];
        }
    } else {                              // ---- wa
        const int o    = (bid - 64) * 256 + tid;
        const int head = o >> 9;
        const int st   = (o >> 8) & 1;
        const int s    = o & 255;
        const float* wr = W + (size_t)s * (H_ * D_) + head * D_;
        const float* ar = a + head * 256 + st * 128;
        float sum = 0.f;
        #pragma unroll
        for (int d = 0; d < 128; d += 4) {
            const float4 wv = *(const float4*)(wr + d);
            const float4 av = *(const float4*)(ar + d);
            sum += wv.x * av.x + wv.y * av.y + wv.z * av.z + wv.w * av.w;
        }
        wa[s * 16 + head * 2 + st] = sum;
    }
}

// ---------------------------------------------------------------------------
// Kernel 1 (merged): [0,1024) LDS 2-phase bf16 MFMA GEMM -> htT[bth][d][n];
// async A-staging split (T14), counted vmcnt(4). [1024,1152) prescaled
// s1/t1 (= proj * L2E). [1152,1664) adjm pair-mask packing.
// ---------------------------------------------------------------------------
__global__ __launch_bounds__(256, 2) void k_gemm_sp(const float* __restrict__ h,
                                                    const unsigned short* __restrict__ Wt_bf,
                                                    const float* __restrict__ wa,
                                                    const int* __restrict__ adj,
                                                    unsigned short* __restrict__ htT,
                                                    float* __restrict__ s1,
                                                    float* __restrict__ t1,
                                                    uint32_t* __restrict__ adjm) {
    __shared__ __align__(16) char smem[24576];
    const int bid = blockIdx.x, tid = threadIdx.x;
    if (bid < 1024) {                     // ---- GEMM
        unsigned short* a_lds = (unsigned short*)smem;            // [2][4096]
        unsigned short* b_lds = (unsigned short*)(smem + 16384);  // [2][2048]
        const int xcd  = bid & 7;
        const int slot = bid >> 3;
        const int gid  = xcd * 8 + (slot >> 4);
        const int bt   = gid >> 3;
        const int n0   = (gid & 7) * 128;
        const int hk0  = (slot & 15) * 64;
        const int w = tid >> 6, lane = tid & 63;
        const int row16 = lane & 15, kgrp = lane >> 4;
        const int kswz = (kgrp ^ ((row16 >> 1) & 3)) * 8;
        const int ar  = tid >> 1;
        const int akh = tid & 1;
        const int asub = ar >> 4, arow = ar & 15;
        const int ax = (arow >> 1) & 3;
        const int aslot0 = ((akh * 2) ^ ax) * 8;
        const int aslot1 = ((akh * 2 + 1) ^ ax) * 8;
        const float* ga = h + ((size_t)bt * N_ + n0 + ar) * FIN_ + akh * 16;
        unsigned short* aw_ = a_lds + asub * 512 + arow * 32;
        const int brow = lane >> 2;
        const int bsb  = (lane & 3) ^ ((lane >> 3) & 3);
        const unsigned short* gb = Wt_bf + (size_t)(hk0 + w * 16 + brow) * FIN_ + bsb * 8;
        unsigned short* bw_ = b_lds + w * 512 + (size_t)lane * 8;

        float4 rf0, rf1, rf2, rf3;    // A-staging register set (1 iter ahead)

#define LOADA(KS) {                                                            \
        const float* g = ga + (KS) * 32;                                       \
        rf0 = *(const float4*)(g);      rf1 = *(const float4*)(g + 4);         \
        rf2 = *(const float4*)(g + 8);  rf3 = *(const float4*)(g + 12); }

#define WRITEA(BUF) {                                                          \
        uint4 o0, o1;                                                          \
        o0.x = cvt_pk_bf16(rf0.x, rf0.y); o0.y = cvt_pk_bf16(rf0.z, rf0.w);    \
        o0.z = cvt_pk_bf16(rf1.x, rf1.y); o0.w = cvt_pk_bf16(rf1.z, rf1.w);    \
        o1.x = cvt_pk_bf16(rf2.x, rf2.y); o1.y = cvt_pk_bf16(rf2.z, rf2.w);    \
        o1.z = cvt_pk_bf16(rf3.x, rf3.y); o1.w = cvt_pk_bf16(rf3.z, rf3.w);    \
        unsigned short* ad = aw_ + (BUF) * 4096;                               \
        *(uint4*)(ad + aslot0) = o0;                                           \
        *(uint4*)(ad + aslot1) = o1; }

#define COMPK(BUF) {                                                           \
        const unsigned short* ab = a_lds + (BUF) * 4096;                       \
        const short8 bfv = *(const short8*)(b_lds + (BUF) * 2048 + w * 512 + row16 * 32 + kswz); \
        _Pragma("unroll")                                                      \
        for (int nt = 0; nt < 8; ++nt) {                                       \
            const short8 afv = *(const short8*)(ab + nt * 512 + row16 * 32 + kswz); \
            acc[nt] = MFMA16(afv, bfv, acc[nt]);                               \
        } }

        f32x4 acc[8];
        #pragma unroll
        for (int nt = 0; nt < 8; ++nt) acc[nt] = (f32x4){0.f, 0.f, 0.f, 0.f};

        LOADA(0)
        WRITEA(0)
        load_lds16(gb, bw_);
        LOADA(1)
        asm volatile("s_waitcnt vmcnt(4) lgkmcnt(0)" ::: "memory");
        __builtin_amdgcn_s_barrier();

        for (int ks = 0; ks < 8; ++ks) {
            const int cur = ks & 1;
            WRITEA(cur ^ 1)                                      // A(ks+1)
            load_lds16(gb + ((ks + 1) & 7) * 32, bw_ + (cur ^ 1) * 2048);
            LOADA((ks + 2) & 7)
            COMPK(cur)
            asm volatile("s_waitcnt vmcnt(4) lgkmcnt(0)" ::: "memory");
            __builtin_amdgcn_s_barrier();
        }
#undef LOADA
#undef WRITEA
#undef COMPK
        const int hk   = hk0 + w * 16 + row16;
        const int head = hk >> 7;
        const int d    = hk & 127;
        unsigned short* ob = htT + ((size_t)(bt * H_ + head) * D_ + d) * N_;
        #pragma unroll
        for (int nt = 0; nt < 8; ++nt) {
            ushort4 v;
            v.x = f2bf(acc[nt][0]); v.y = f2bf(acc[nt][1]);
            v.z = f2bf(acc[nt][2]); v.w = f2bf(acc[nt][3]);
            *(ushort4*)(ob + n0 + nt * 16 + kgrp * 4) = v;
        }
    } else if (bid < 1152) {              // ---- prescaled src/tgt projections
        float (*was)[16] = (float(*)[16])smem;
        {
            const int f = tid * 16;
            #pragma unroll
            for (int k = 0; k < 4; ++k)
                *(float4*)&was[f >> 4][k * 4] = *(const float4*)(wa + f + k * 4);
        }
        __syncthreads();
        const int r = tid >> 2, q = tid & 3;
        const int R = (bid - 1024) * 64 + r;
        const float* hrow = h + (size_t)R * FIN_ + q * 64;
        float acc[16];
        #pragma unroll
        for (int o = 0; o < 16; ++o) acc[o] = 0.f;
        for (int k = 0; k < 64; k += 4) {
            const float4 hv = *(const float4*)(hrow + k);
            const int s = q * 64 + k;
            #pragma unroll
            for (int kk = 0; kk < 4; ++kk) {
                const float hs = (kk == 0) ? hv.x : (kk == 1) ? hv.y : (kk == 2) ? hv.z : hv.w;
                #pragma unroll
                for (int o = 0; o < 16; ++o) acc[o] += hs * was[s + kk][o];
            }
        }
        #pragma unroll
        for (int o = 0; o < 16; ++o) {
            acc[o] += __shfl_xor(acc[o], 1);
            acc[o] += __shfl_xor(acc[o], 2);
        }
        const int bt = R >> 10, n = R & 1023;
        #pragma unroll
        for (int k = 0; k < 4; ++k) {
            const int o = q * 4 + k;
            const int head = o >> 1;
            const size_t idx = ((size_t)(bt * H_ + head)) * N_ + n;
            const float v = acc[o] * L2E_;
            if (o & 1) t1[idx] = v;
            else       s1[idx] = v;
        }
    } else {                              // ---- adjm pair-mask packing
        const int w0 = ((bid - 1152) * 256 + tid) * 4;
        const int4 p0 = *(const int4*)(adj + (size_t)w0 * 2);
        const int4 p1 = *(const int4*)(adj + (size_t)w0 * 2 + 4);
        uint4 m;
        m.x = (p0.x > 0 ? 0xFFFFu : 0u) | (p0.y > 0 ? 0xFFFF0000u : 0u);
        m.y = (p0.z > 0 ? 0xFFFFu : 0u) | (p0.w > 0 ? 0xFFFF0000u : 0u);
        m.z = (p1.x > 0 ? 0xFFFFu : 0u) | (p1.y > 0 ? 0xFFFF0000u : 0u);
        m.w = (p1.z > 0 ? 0xFFFFu : 0u) | (p1.w > 0 ? 0xFFFF0000u : 0u);
        *(uint4*)(adjm + w0) = m;
    }
}

// score-operand register set (statically addressed struct; rule-20 safe)
struct SC {
    float4 a1l, a1h;      // t1 (prescaled tgt*L2E) for 8 j
    uint4  m4A, m4B;      // pair-masks for rows iA / iB (8 j)
};

// ---------------------------------------------------------------------------
// Kernel 2: fused mask+softmax+PV via MFMA — R13 structure verbatim (best
// measured: k_attn < 45us). grid 512 (XCD-swizzled), block 256 = 4 waves;
// wave = 32 i-rows dual-chain (A=rows iA, B=iA+16 share B-frag reads) x one
// b. LDS: 4 x 16KB buffers, XOR-swizzled. 64-j iters (2 sub-phases), counted
// vmcnt(8) (= 8 sc loads issued after the pair's 8 stage loads). Lean scores
// (e2 = 0.2*e1, pair-mask AND on cvt_pk output), raw v_exp_f32, ones-column
// MFMA denominator, cross-b mean epilogue in LDS.
// ---------------------------------------------------------------------------
__global__ __launch_bounds__(256, 2) void k_attn(const unsigned short* __restrict__ htT,
                                                 const float* __restrict__ s1,
                                                 const float* __restrict__ t1,
                                                 const uint32_t* __restrict__ adjm,
                                                 float* __restrict__ out) {
    __shared__ __align__(16) char smem[65536];
    unsigned short* stg = (unsigned short*)smem;   // 4 bufs x 8192 shorts
    const int xcd  = blockIdx.x & 7;
    const int slot = blockIdx.x >> 3;
    const int th   = xcd * 4 + (slot >> 4);
    const int i0   = (slot & 15) * 64;
    const int tid = threadIdx.x;
    const int w = tid >> 6, lane = tid & 63;
    const int b = w & 1, isub = w >> 1;
    const int row16 = lane & 15, kgrp = lane >> 4, jrel = kgrp * 8;
    const int kswz = (kgrp ^ ((row16 >> 1) & 3)) * 8;
    const int bth = b * (T_ * H_) + th;
    const int iA  = i0 + isub * 32 + row16;
    const int iB  = iA + 16;
    const float s1A = s1[(size_t)bth * N_ + iA];
    const float s1B = s1[(size_t)bth * N_ + iB];
    const f32x2 s1A2 = {s1A, s1A}, s1B2 = {s1B, s1B};
    const f32x2 c02  = {0.2f, 0.2f};
    const float* t1b = t1 + (size_t)bth * N_;
    const uint32_t* amA = adjm + (size_t)iA * (N_ / 2);
    const uint32_t* amB = adjm + (size_t)iB * (N_ / 2);

    // staging: wave w fills quarter w; source j pre-swizzled (slot ^ (d>>1)&3)
    const int sb  = w >> 1;
    const int sd0 = (w & 1) * 64 + (lane >> 2);
    const int sj  = ((lane & 3) ^ ((lane >> 3) & 3)) * 8;
    const unsigned short* gstg = htT + ((size_t)(sb * (T_ * H_) + th) * D_ + sd0) * N_ + sj;
    unsigned short* lstg = stg + (size_t)w * 2048 + (size_t)lane * 8;

#define STAGE(BUF, T32) {                                        \
        const unsigned short* gs = gstg + (size_t)(T32) * 32;    \
        unsigned short* ls = lstg + (BUF) * 8192;                \
        load_lds16(gs,           ls);                            \
        load_lds16(gs + 16 * N_, ls + 512);                      \
        load_lds16(gs + 32 * N_, ls + 1024);                     \
        load_lds16(gs + 48 * N_, ls + 1536); }

#define LOADSC(S, T32) {                                         \
        S.a1l = *(const float4*)(t1b + (T32) * 32 + jrel);       \
        S.a1h = *(const float4*)(t1b + (T32) * 32 + jrel + 4);   \
        S.m4A = *(const uint4*)(amA + (T32) * 16 + kgrp * 4);    \
        S.m4B = *(const uint4*)(amB + (T32) * 16 + kgrp * 4); }

    f32x4 accA[8], accB[8];
    #pragma unroll
    for (int nt = 0; nt < 8; ++nt) {
        accA[nt] = (f32x4){0.f, 0.f, 0.f, 0.f};
        accB[nt] = (f32x4){0.f, 0.f, 0.f, 0.f};
    }
    f32x4 daccA = (f32x4){0.f, 0.f, 0.f, 0.f};
    f32x4 daccB = (f32x4){0.f, 0.f, 0.f, 0.f};
    short8 ones8;
    {
        const short ov = (row16 == 0) ? (short)0x3F80 : (short)0;
        #pragma unroll
        for (int e = 0; e < 8; ++e) ones8[e] = ov;
    }
    const unsigned short* rdbase = stg + b * 4096 + row16 * 32 + kswz;

    SC scA, scB;

    // sub-phase: consume SCS -> af frags (lean path); reload SCS; ds_read; MFMA
#define SUBP(BUFIDX, SCS, TNEXT)                                               \
    {                                                                          \
        const f32x2 tq[4] = {{SCS.a1l.x, SCS.a1l.y}, {SCS.a1l.z, SCS.a1l.w},   \
                             {SCS.a1h.x, SCS.a1h.y}, {SCS.a1h.z, SCS.a1h.w}};  \
        const uint32_t mAw[4] = {SCS.m4A.x, SCS.m4A.y, SCS.m4A.z, SCS.m4A.w};  \
        const uint32_t mBw[4] = {SCS.m4B.x, SCS.m4B.y, SCS.m4B.z, SCS.m4B.w};  \
        short8 afA, afB;                                                       \
        _Pragma("unroll")                                                      \
        for (int p = 0; p < 4; ++p) {                                          \
            const f32x2 eA  = s1A2 + tq[p];                                    \
            const f32x2 eB  = s1B2 + tq[p];                                    \
            const f32x2 eA2 = eA * c02;                                        \
            const f32x2 eB2 = eB * c02;                                        \
            const float wA0 = fexp2(fmaxf(eA[0], eA2[0]));                     \
            const float wA1 = fexp2(fmaxf(eA[1], eA2[1]));                     \
            const float wB0 = fexp2(fmaxf(eB[0], eB2[0]));                     \
            const float wB1 = fexp2(fmaxf(eB[1], eB2[1]));                     \
            ((uint32_t*)&afA)[p] = cvt_pk_bf16(wA0, wA1) & mAw[p];             \
            ((uint32_t*)&afB)[p] = cvt_pk_bf16(wB0, wB1) & mBw[p];             \
        }                                                                      \
        LOADSC(SCS, (TNEXT))                                                   \
        const unsigned short* rb = rdbase + (BUFIDX) * 8192;                   \
        short8 bfr[8];                                                         \
        _Pragma("unroll")                                                      \
        for (int nt = 0; nt < 8; ++nt) bfr[nt] = *(const short8*)(rb + nt * 512); \
        _Pragma("unroll")                                                      \
        for (int nt = 0; nt < 8; ++nt) {                                       \
            accA[nt] = MFMA16(afA, bfr[nt], accA[nt]);                         \
            accB[nt] = MFMA16(afB, bfr[nt], accB[nt]);                         \
        }                                                                      \
        daccA = MFMA16(afA, ones8, daccA);                                     \
        daccB = MFMA16(afB, ones8, daccB);                                     \
    }

    STAGE(0, 0)
    STAGE(1, 1)
    LOADSC(scA, 0)
    LOADSC(scB, 1)

    for (int T = 0; T < 16; ++T) {
        const int pair  = T & 1;
        const int npair = pair ^ 1;
        asm volatile("s_waitcnt vmcnt(8)" ::: "memory");
        __builtin_amdgcn_s_barrier();
        asm volatile("" ::: "memory");
        STAGE(npair * 2,     (2 * T + 2) & 31)
        STAGE(npair * 2 + 1, (2 * T + 3) & 31)
        SUBP(pair * 2,     scA, (2 * T + 2) & 31)
        SUBP(pair * 2 + 1, scB, (2 * T + 3) & 31)
    }
#undef SUBP
#undef LOADSC
#undef STAGE

    __syncthreads();   // full drain (incl. wraparound stages) before LDS reuse

    // inverse denominators: D[row=kgrp*4+r][0] lives at lane kgrp*16, reg r
    float ivA[4], ivB[4];
    #pragma unroll
    for (int r = 0; r < 4; ++r) {
        ivA[r] = __shfl(1.0f / daccA[r], kgrp * 16);
        ivB[r] = __shfl(1.0f / daccB[r], kgrp * 16);
    }

    // cross-b mean via LDS (reuse stage memory: 64 rows x 128 f32 = 32KB)
    float* comb = (float*)smem;
    if (b == 1) {
        #pragma unroll
        for (int nt = 0; nt < 8; ++nt)
            #pragma unroll
            for (int r = 0; r < 4; ++r) {
                const int il = isub * 32 + kgrp * 4 + r;
                const int d  = nt * 16 + row16;
                comb[il * 128 + d]        = accA[nt][r] * ivA[r];
                comb[(il + 16) * 128 + d] = accB[nt][r] * ivB[r];
            }
    }
    __syncthreads();
    if (b == 0) {
        #pragma unroll
        for (int nt = 0; nt < 8; ++nt)
            #pragma unroll
            for (int r = 0; r < 4; ++r) {
                const int il = isub * 32 + kgrp * 4 + r;
                const int d  = nt * 16 + row16;
                out[((size_t)th * N_ + i0 + il) * D_ + d] =
                    0.5f * (accA[nt][r] * ivA[r] + comb[il * 128 + d]);
                out[((size_t)th * N_ + i0 + il + 16) * D_ + d] =
                    0.5f * (accB[nt][r] * ivB[r] + comb[(il + 16) * 128 + d]);
            }
    }
}

extern "C" void kernel_launch(void* const* d_in, const int* in_sizes, int n_in,
                              void* d_out, int out_size, void* d_ws, size_t ws_size,
                              hipStream_t stream) {
    const float* h   = (const float*)d_in[0];
    const int*   adj = (const int*)d_in[1];
    const float* W   = (const float*)d_in[2];
    const float* a   = (const float*)d_in[3];
    float* out = (float*)d_out;

    // ws: htT 16.78MB | s1,t1 2x256KB | adjm 2MB | Wt_bf 512KB | wa 16KB
    char* p = (char*)d_ws;
    unsigned short* htT = (unsigned short*)p;  p += (size_t)B_ * T_ * H_ * D_ * N_ * 2;
    float* s1 = (float*)p;                     p += (size_t)B_ * T_ * H_ * N_ * 4;
    float* t1 = (float*)p;                     p += (size_t)B_ * T_ * H_ * N_ * 4;
    uint32_t* adjm = (uint32_t*)p;             p += (size_t)N_ * N_ / 2 * 4;
    unsigned short* Wt_bf = (unsigned short*)p;p += (size_t)(H_ * D_) * FIN_ * 2;
    float* wa = (float*)p;

    k_prep<<<dim3(80), dim3(256), 0, stream>>>(W, a, Wt_bf, wa);
    k_gemm_sp<<<dim3(1664), dim3(256), 0, stream>>>(h, Wt_bf, wa, adj, htT, s1, t1, adjm);
    k_attn<<<dim3(512), dim3(256), 0, stream>>>(htT, s1, t1, adjm, out);
}

// Round 19
// 65.934 us; speedup vs baseline: 1.2748x; 1.0776x over previous
//
#include <hip/hip_runtime.h>
#include <cstddef>
#include <cstdint>

#define B_ 2
#define T_ 4
#define N_ 1024
#define FIN_ 256
#define H_ 8
#define D_ 128
#define L2E_ 1.4426950408889634f

typedef __attribute__((ext_vector_type(8))) short short8;
typedef __attribute__((ext_vector_type(4))) float f32x4;
typedef __attribute__((ext_vector_type(2))) float f32x2;

#define MFMA16(A, B, C) __builtin_amdgcn_mfma_f32_16x16x32_bf16((A), (B), (C), 0, 0, 0)

__device__ __forceinline__ unsigned short f2bf(float f) {
    uint32_t u = __float_as_uint(f);
    uint32_t r = (u + 0x7fffu + ((u >> 16) & 1u)) >> 16;   // RNE
    return (unsigned short)r;
}

__device__ __forceinline__ uint32_t cvt_pk_bf16(float lo, float hi) {
    uint32_t r;
    asm volatile("v_cvt_pk_bf16_f32 %0, %1, %2" : "=v"(r) : "v"(lo), "v"(hi));
    return r;
}

// raw v_exp_f32 (2^x) — avoids OCML guarded exp2f expansion
__device__ __forceinline__ float fexp2(float x) {
#if __has_builtin(__builtin_amdgcn_exp2f)
    return __builtin_amdgcn_exp2f(x);
#else
    float r;
    asm("v_exp_f32 %0, %1" : "=v"(r) : "v"(x));
    return r;
#endif
}

// async global->LDS, 16B per lane (dest = wave base + lane*16)
__device__ __forceinline__ void load_lds16(const unsigned short* g, unsigned short* l) {
    __builtin_amdgcn_global_load_lds(
        (const __attribute__((address_space(1))) uint32_t*)g,
        (__attribute__((address_space(3))) uint32_t*)l, 16, 0, 0);
}

// ---------------------------------------------------------------------------
// Kernel 0 (prep, tiny): [0,64) W [s][hk] -> Wt_bf [hk][s] bf16;
// [64,80) wa[s][head*2+st] = sum_d W[s][head*128+d]*a[head*256+st*128+d]
// ---------------------------------------------------------------------------
__global__ __launch_bounds__(256) void k_prep(const float* __restrict__ W,
                                              const float* __restrict__ a,
                                              unsigned short* __restrict__ Wt_bf,
                                              float* __restrict__ wa) {
    __shared__ float wl[64][68];
    const int bid = blockIdx.x, tid = threadIdx.x;
    if (bid < 64) {                       // ---- W transpose -> bf16
        const int tb  = bid;
        const int hk0 = (tb >> 2) * 64;
        const int s0  = (tb & 3) * 64;
        {
            const int r  = tid >> 2;
            const int c0 = (tid & 3) * 16;
            #pragma unroll
            for (int k = 0; k < 4; ++k)
                *(float4*)&wl[r][c0 + k * 4] =
                    *(const float4*)(W + (size_t)(s0 + r) * (H_ * D_) + hk0 + c0 + k * 4);
        }
        __syncthreads();
        {
            const int r2 = tid >> 2;
            const int c2 = (tid & 3) * 16;
            unsigned short ob[16];
            #pragma unroll
            for (int k = 0; k < 16; ++k) ob[k] = f2bf(wl[c2 + k][r2]);
            unsigned short* dst = Wt_bf + (size_t)(hk0 + r2) * FIN_ + s0 + c2;
            *(uint4*)(dst)     = *(uint4*)&ob[0];
            *(uint4*)(dst + 8) = *(uint4*)&ob[8];
        }
    } else {                              // ---- wa
        const int o    = (bid - 64) * 256 + tid;
        const int head = o >> 9;
        const int st   = (o >> 8) & 1;
        const int s    = o & 255;
        const float* wr = W + (size_t)s * (H_ * D_) + head * D_;
        const float* ar = a + head * 256 + st * 128;
        float sum = 0.f;
        #pragma unroll
        for (int d = 0; d < 128; d += 4) {
            const float4 wv = *(const float4*)(wr + d);
            const float4 av = *(const float4*)(ar + d);
            sum += wv.x * av.x + wv.y * av.y + wv.z * av.z + wv.w * av.w;
        }
        wa[s * 16 + head * 2 + st] = sum;
    }
}

// ---------------------------------------------------------------------------
// Kernel 1 (merged): [0,512) LDS 2-phase bf16 MFMA GEMM, WIDE 128n x 128hk
// tile (one head per block) -> htT[bth][d][n]; T14 A-staging, counted
// vmcnt(4). [512,640) prescaled s1/t1. [640,1152) adjm pair-mask packing.
// ---------------------------------------------------------------------------
__global__ __launch_bounds__(256, 2) void k_gemm_sp(const float* __restrict__ h,
                                                    const unsigned short* __restrict__ Wt_bf,
                                                    const float* __restrict__ wa,
                                                    const int* __restrict__ adj,
                                                    unsigned short* __restrict__ htT,
                                                    float* __restrict__ s1,
                                                    float* __restrict__ t1,
                                                    uint32_t* __restrict__ adjm) {
    __shared__ __align__(16) char smem[32768];
    const int bid = blockIdx.x, tid = threadIdx.x;
    if (bid < 512) {                      // ---- GEMM (128n x 128hk)
        unsigned short* a_lds = (unsigned short*)smem;            // [2][4096] shorts
        unsigned short* b_lds = (unsigned short*)(smem + 16384);  // [2][4096] shorts
        const int xcd  = bid & 7;
        const int slot = bid >> 3;                 // 0..63
        const int gid  = xcd * 8 + (slot >> 3);    // 0..63 = (bt, n0)
        const int bt   = gid >> 3;
        const int n0   = (gid & 7) * 128;
        const int hk0  = (slot & 7) * 128;         // one full head per block
        const int head = hk0 >> 7;
        const int w = tid >> 6, lane = tid & 63;
        const int row16 = lane & 15, kgrp = lane >> 4;
        const int kswz = (kgrp ^ ((row16 >> 1) & 3)) * 8;
        // A staging mapping (T14 register path; n-tile 128 rows)
        const int ar  = tid >> 1;
        const int akh = tid & 1;
        const int asub = ar >> 4, arow = ar & 15;
        const int ax = (arow >> 1) & 3;
        const int aslot0 = ((akh * 2) ^ ax) * 8;
        const int aslot1 = ((akh * 2 + 1) ^ ax) * 8;
        const float* ga = h + ((size_t)bt * N_ + n0 + ar) * FIN_ + akh * 16;
        unsigned short* aw_ = a_lds + asub * 512 + arow * 32;
        // B staging: wave w stages its 32 hk rows (2 x load_lds16 per k-step)
        const int brow = lane >> 2;                 // 0..15
        const int bsb  = (lane & 3) ^ ((lane >> 3) & 3);
        const unsigned short* gb = Wt_bf + (size_t)(hk0 + w * 32 + brow) * FIN_ + bsb * 8;
        unsigned short* bw_ = b_lds + w * 1024 + (size_t)lane * 8;

        float4 rf0, rf1, rf2, rf3;    // A-staging register set (1 iter ahead)

#define LOADA(KS) {                                                            \
        const float* g = ga + (KS) * 32;                                       \
        rf0 = *(const float4*)(g);      rf1 = *(const float4*)(g + 4);         \
        rf2 = *(const float4*)(g + 8);  rf3 = *(const float4*)(g + 12); }

#define WRITEA(BUF) {                                                          \
        uint4 o0, o1;                                                          \
        o0.x = cvt_pk_bf16(rf0.x, rf0.y); o0.y = cvt_pk_bf16(rf0.z, rf0.w);    \
        o0.z = cvt_pk_bf16(rf1.x, rf1.y); o0.w = cvt_pk_bf16(rf1.z, rf1.w);    \
        o1.x = cvt_pk_bf16(rf2.x, rf2.y); o1.y = cvt_pk_bf16(rf2.z, rf2.w);    \
        o1.z = cvt_pk_bf16(rf3.x, rf3.y); o1.w = cvt_pk_bf16(rf3.z, rf3.w);    \
        unsigned short* ad = aw_ + (BUF) * 4096;                               \
        *(uint4*)(ad + aslot0) = o0;                                           \
        *(uint4*)(ad + aslot1) = o1; }

#define STAGEB(BUF, KS) {                                                      \
        const unsigned short* gsb = gb + (KS) * 32;                            \
        unsigned short* lsb = bw_ + (BUF) * 4096;                              \
        load_lds16(gsb,             lsb);                                      \
        load_lds16(gsb + 16 * FIN_, lsb + 512); }

#define COMPK(BUF) {                                                           \
        const unsigned short* ab = a_lds + (BUF) * 4096;                       \
        const unsigned short* bb = b_lds + (BUF) * 4096 + w * 1024;            \
        const short8 bf0 = *(const short8*)(bb + row16 * 32 + kswz);           \
        const short8 bf1 = *(const short8*)(bb + 512 + row16 * 32 + kswz);     \
        _Pragma("unroll")                                                      \
        for (int nt = 0; nt < 8; ++nt) {                                       \
            const short8 afv = *(const short8*)(ab + nt * 512 + row16 * 32 + kswz); \
            acc0[nt] = MFMA16(afv, bf0, acc0[nt]);                             \
            acc1[nt] = MFMA16(afv, bf1, acc1[nt]);                             \
        } }

        f32x4 acc0[8], acc1[8];
        #pragma unroll
        for (int nt = 0; nt < 8; ++nt) {
            acc0[nt] = (f32x4){0.f, 0.f, 0.f, 0.f};
            acc1[nt] = (f32x4){0.f, 0.f, 0.f, 0.f};
        }

        LOADA(0)
        WRITEA(0)
        STAGEB(0, 0)
        LOADA(1)
        asm volatile("s_waitcnt vmcnt(4) lgkmcnt(0)" ::: "memory");
        __builtin_amdgcn_s_barrier();

        for (int ks = 0; ks < 8; ++ks) {
            const int cur = ks & 1;
            WRITEA(cur ^ 1)                                      // A(ks+1)
            STAGEB(cur ^ 1, (ks + 1) & 7)                        // B(ks+1)
            LOADA((ks + 2) & 7)
            COMPK(cur)
            asm volatile("s_waitcnt vmcnt(4) lgkmcnt(0)" ::: "memory");
            __builtin_amdgcn_s_barrier();
        }
#undef LOADA
#undef WRITEA
#undef STAGEB
#undef COMPK
        // store: d = w*32 + f*16 + row16, n = n0 + nt*16 + kgrp*4
        unsigned short* ob0 = htT + ((size_t)(bt * H_ + head) * D_ + w * 32 + row16) * N_;
        unsigned short* ob1 = ob0 + 16 * N_;
        #pragma unroll
        for (int nt = 0; nt < 8; ++nt) {
            ushort4 v0, v1;
            v0.x = f2bf(acc0[nt][0]); v0.y = f2bf(acc0[nt][1]);
            v0.z = f2bf(acc0[nt][2]); v0.w = f2bf(acc0[nt][3]);
            v1.x = f2bf(acc1[nt][0]); v1.y = f2bf(acc1[nt][1]);
            v1.z = f2bf(acc1[nt][2]); v1.w = f2bf(acc1[nt][3]);
            *(ushort4*)(ob0 + n0 + nt * 16 + kgrp * 4) = v0;
            *(ushort4*)(ob1 + n0 + nt * 16 + kgrp * 4) = v1;
        }
    } else if (bid < 640) {               // ---- prescaled src/tgt projections
        float (*was)[16] = (float(*)[16])smem;
        {
            const int f = tid * 16;
            #pragma unroll
            for (int k = 0; k < 4; ++k)
                *(float4*)&was[f >> 4][k * 4] = *(const float4*)(wa + f + k * 4);
        }
        __syncthreads();
        const int r = tid >> 2, q = tid & 3;
        const int R = (bid - 512) * 64 + r;
        const float* hrow = h + (size_t)R * FIN_ + q * 64;
        float acc[16];
        #pragma unroll
        for (int o = 0; o < 16; ++o) acc[o] = 0.f;
        for (int k = 0; k < 64; k += 4) {
            const float4 hv = *(const float4*)(hrow + k);
            const int s = q * 64 + k;
            #pragma unroll
            for (int kk = 0; kk < 4; ++kk) {
                const float hs = (kk == 0) ? hv.x : (kk == 1) ? hv.y : (kk == 2) ? hv.z : hv.w;
                #pragma unroll
                for (int o = 0; o < 16; ++o) acc[o] += hs * was[s + kk][o];
            }
        }
        #pragma unroll
        for (int o = 0; o < 16; ++o) {
            acc[o] += __shfl_xor(acc[o], 1);
            acc[o] += __shfl_xor(acc[o], 2);
        }
        const int bt = R >> 10, n = R & 1023;
        #pragma unroll
        for (int k = 0; k < 4; ++k) {
            const int o = q * 4 + k;
            const int head = o >> 1;
            const size_t idx = ((size_t)(bt * H_ + head)) * N_ + n;
            const float v = acc[o] * L2E_;
            if (o & 1) t1[idx] = v;
            else       s1[idx] = v;
        }
    } else {                              // ---- adjm pair-mask packing
        const int w0 = ((bid - 640) * 256 + tid) * 4;
        const int4 p0 = *(const int4*)(adj + (size_t)w0 * 2);
        const int4 p1 = *(const int4*)(adj + (size_t)w0 * 2 + 4);
        uint4 m;
        m.x = (p0.x > 0 ? 0xFFFFu : 0u) | (p0.y > 0 ? 0xFFFF0000u : 0u);
        m.y = (p0.z > 0 ? 0xFFFFu : 0u) | (p0.w > 0 ? 0xFFFF0000u : 0u);
        m.z = (p1.x > 0 ? 0xFFFFu : 0u) | (p1.y > 0 ? 0xFFFF0000u : 0u);
        m.w = (p1.z > 0 ? 0xFFFFu : 0u) | (p1.w > 0 ? 0xFFFF0000u : 0u);
        *(uint4*)(adjm + w0) = m;
    }
}

// score-operand register set (statically addressed struct; rule-20 safe)
struct SC {
    float4 a1l, a1h;      // t1 (prescaled tgt*L2E) for 8 j
    uint4  m4A, m4B;      // pair-masks for rows iA / iB (8 j)
};

// ---------------------------------------------------------------------------
// Kernel 2: fused mask+softmax+PV via MFMA — R13/R18 structure verbatim (best
// measured: k_attn < 45us). grid 512 (XCD-swizzled), block 256 = 4 waves;
// wave = 32 i-rows dual-chain (A=rows iA, B=iA+16 share B-frag reads) x one
// b. LDS: 4 x 16KB buffers, XOR-swizzled. 64-j iters (2 sub-phases), counted
// vmcnt(8). Lean scores (e2 = 0.2*e1, pair-mask AND), raw v_exp_f32,
// ones-column MFMA denominator, cross-b mean epilogue in LDS.
// ---------------------------------------------------------------------------
__global__ __launch_bounds__(256, 2) void k_attn(const unsigned short* __restrict__ htT,
                                                 const float* __restrict__ s1,
                                                 const float* __restrict__ t1,
                                                 const uint32_t* __restrict__ adjm,
                                                 float* __restrict__ out) {
    __shared__ __align__(16) char smem[65536];
    unsigned short* stg = (unsigned short*)smem;   // 4 bufs x 8192 shorts
    const int xcd  = blockIdx.x & 7;
    const int slot = blockIdx.x >> 3;
    const int th   = xcd * 4 + (slot >> 4);
    const int i0   = (slot & 15) * 64;
    const int tid = threadIdx.x;
    const int w = tid >> 6, lane = tid & 63;
    const int b = w & 1, isub = w >> 1;
    const int row16 = lane & 15, kgrp = lane >> 4, jrel = kgrp * 8;
    const int kswz = (kgrp ^ ((row16 >> 1) & 3)) * 8;
    const int bth = b * (T_ * H_) + th;
    const int iA  = i0 + isub * 32 + row16;
    const int iB  = iA + 16;
    const float s1A = s1[(size_t)bth * N_ + iA];
    const float s1B = s1[(size_t)bth * N_ + iB];
    const f32x2 s1A2 = {s1A, s1A}, s1B2 = {s1B, s1B};
    const f32x2 c02  = {0.2f, 0.2f};
    const float* t1b = t1 + (size_t)bth * N_;
    const uint32_t* amA = adjm + (size_t)iA * (N_ / 2);
    const uint32_t* amB = adjm + (size_t)iB * (N_ / 2);

    // staging: wave w fills quarter w; source j pre-swizzled (slot ^ (d>>1)&3)
    const int sb  = w >> 1;
    const int sd0 = (w & 1) * 64 + (lane >> 2);
    const int sj  = ((lane & 3) ^ ((lane >> 3) & 3)) * 8;
    const unsigned short* gstg = htT + ((size_t)(sb * (T_ * H_) + th) * D_ + sd0) * N_ + sj;
    unsigned short* lstg = stg + (size_t)w * 2048 + (size_t)lane * 8;

#define STAGE(BUF, T32) {                                        \
        const unsigned short* gs = gstg + (size_t)(T32) * 32;    \
        unsigned short* ls = lstg + (BUF) * 8192;                \
        load_lds16(gs,           ls);                            \
        load_lds16(gs + 16 * N_, ls + 512);                      \
        load_lds16(gs + 32 * N_, ls + 1024);                     \
        load_lds16(gs + 48 * N_, ls + 1536); }

#define LOADSC(S, T32) {                                         \
        S.a1l = *(const float4*)(t1b + (T32) * 32 + jrel);       \
        S.a1h = *(const float4*)(t1b + (T32) * 32 + jrel + 4);   \
        S.m4A = *(const uint4*)(amA + (T32) * 16 + kgrp * 4);    \
        S.m4B = *(const uint4*)(amB + (T32) * 16 + kgrp * 4); }

    f32x4 accA[8], accB[8];
    #pragma unroll
    for (int nt = 0; nt < 8; ++nt) {
        accA[nt] = (f32x4){0.f, 0.f, 0.f, 0.f};
        accB[nt] = (f32x4){0.f, 0.f, 0.f, 0.f};
    }
    f32x4 daccA = (f32x4){0.f, 0.f, 0.f, 0.f};
    f32x4 daccB = (f32x4){0.f, 0.f, 0.f, 0.f};
    short8 ones8;
    {
        const short ov = (row16 == 0) ? (short)0x3F80 : (short)0;
        #pragma unroll
        for (int e = 0; e < 8; ++e) ones8[e] = ov;
    }
    const unsigned short* rdbase = stg + b * 4096 + row16 * 32 + kswz;

    SC scA, scB;

    // sub-phase: consume SCS -> af frags (lean path); reload SCS; ds_read; MFMA
#define SUBP(BUFIDX, SCS, TNEXT)                                               \
    {                                                                          \
        const f32x2 tq[4] = {{SCS.a1l.x, SCS.a1l.y}, {SCS.a1l.z, SCS.a1l.w},   \
                             {SCS.a1h.x, SCS.a1h.y}, {SCS.a1h.z, SCS.a1h.w}};  \
        const uint32_t mAw[4] = {SCS.m4A.x, SCS.m4A.y, SCS.m4A.z, SCS.m4A.w};  \
        const uint32_t mBw[4] = {SCS.m4B.x, SCS.m4B.y, SCS.m4B.z, SCS.m4B.w};  \
        short8 afA, afB;                                                       \
        _Pragma("unroll")                                                      \
        for (int p = 0; p < 4; ++p) {                                          \
            const f32x2 eA  = s1A2 + tq[p];                                    \
            const f32x2 eB  = s1B2 + tq[p];                                    \
            const f32x2 eA2 = eA * c02;                                        \
            const f32x2 eB2 = eB * c02;                                        \
            const float wA0 = fexp2(fmaxf(eA[0], eA2[0]));                     \
            const float wA1 = fexp2(fmaxf(eA[1], eA2[1]));                     \
            const float wB0 = fexp2(fmaxf(eB[0], eB2[0]));                     \
            const float wB1 = fexp2(fmaxf(eB[1], eB2[1]));                     \
            ((uint32_t*)&afA)[p] = cvt_pk_bf16(wA0, wA1) & mAw[p];             \
            ((uint32_t*)&afB)[p] = cvt_pk_bf16(wB0, wB1) & mBw[p];             \
        }                                                                      \
        LOADSC(SCS, (TNEXT))                                                   \
        const unsigned short* rb = rdbase + (BUFIDX) * 8192;                   \
        short8 bfr[8];                                                         \
        _Pragma("unroll")                                                      \
        for (int nt = 0; nt < 8; ++nt) bfr[nt] = *(const short8*)(rb + nt * 512); \
        _Pragma("unroll")                                                      \
        for (int nt = 0; nt < 8; ++nt) {                                       \
            accA[nt] = MFMA16(afA, bfr[nt], accA[nt]);                         \
            accB[nt] = MFMA16(afB, bfr[nt], accB[nt]);                         \
        }                                                                      \
        daccA = MFMA16(afA, ones8, daccA);                                     \
        daccB = MFMA16(afB, ones8, daccB);                                     \
    }

    STAGE(0, 0)
    STAGE(1, 1)
    LOADSC(scA, 0)
    LOADSC(scB, 1)

    for (int T = 0; T < 16; ++T) {
        const int pair  = T & 1;
        const int npair = pair ^ 1;
        asm volatile("s_waitcnt vmcnt(8)" ::: "memory");
        __builtin_amdgcn_s_barrier();
        asm volatile("" ::: "memory");
        STAGE(npair * 2,     (2 * T + 2) & 31)
        STAGE(npair * 2 + 1, (2 * T + 3) & 31)
        SUBP(pair * 2,     scA, (2 * T + 2) & 31)
        SUBP(pair * 2 + 1, scB, (2 * T + 3) & 31)
    }
#undef SUBP
#undef LOADSC
#undef STAGE

    __syncthreads();   // full drain (incl. wraparound stages) before LDS reuse

    // inverse denominators: D[row=kgrp*4+r][0] lives at lane kgrp*16, reg r
    float ivA[4], ivB[4];
    #pragma unroll
    for (int r = 0; r < 4; ++r) {
        ivA[r] = __shfl(1.0f / daccA[r], kgrp * 16);
        ivB[r] = __shfl(1.0f / daccB[r], kgrp * 16);
    }

    // cross-b mean via LDS (reuse stage memory: 64 rows x 128 f32 = 32KB)
    float* comb = (float*)smem;
    if (b == 1) {
        #pragma unroll
        for (int nt = 0; nt < 8; ++nt)
            #pragma unroll
            for (int r = 0; r < 4; ++r) {
                const int il = isub * 32 + kgrp * 4 + r;
                const int d  = nt * 16 + row16;
                comb[il * 128 + d]        = accA[nt][r] * ivA[r];
                comb[(il + 16) * 128 + d] = accB[nt][r] * ivB[r];
            }
    }
    __syncthreads();
    if (b == 0) {
        #pragma unroll
        for (int nt = 0; nt < 8; ++nt)
            #pragma unroll
            for (int r = 0; r < 4; ++r) {
                const int il = isub * 32 + kgrp * 4 + r;
                const int d  = nt * 16 + row16;
                out[((size_t)th * N_ + i0 + il) * D_ + d] =
                    0.5f * (accA[nt][r] * ivA[r] + comb[il * 128 + d]);
                out[((size_t)th * N_ + i0 + il + 16) * D_ + d] =
                    0.5f * (accB[nt][r] * ivB[r] + comb[(il + 16) * 128 + d]);
            }
    }
}

extern "C" void kernel_launch(void* const* d_in, const int* in_sizes, int n_in,
                              void* d_out, int out_size, void* d_ws, size_t ws_size,
                              hipStream_t stream) {
    const float* h   = (const float*)d_in[0];
    const int*   adj = (const int*)d_in[1];
    const float* W   = (const float*)d_in[2];
    const float* a   = (const float*)d_in[3];
    float* out = (float*)d_out;

    // ws: htT 16.78MB | s1,t1 2x256KB | adjm 2MB | Wt_bf 512KB | wa 16KB
    char* p = (char*)d_ws;
    unsigned short* htT = (unsigned short*)p;  p += (size_t)B_ * T_ * H_ * D_ * N_ * 2;
    float* s1 = (float*)p;                     p += (size_t)B_ * T_ * H_ * N_ * 4;
    float* t1 = (float*)p;                     p += (size_t)B_ * T_ * H_ * N_ * 4;
    uint32_t* adjm = (uint32_t*)p;             p += (size_t)N_ * N_ / 2 * 4;
    unsigned short* Wt_bf = (unsigned short*)p;p += (size_t)(H_ * D_) * FIN_ * 2;
    float* wa = (float*)p;

    k_prep<<<dim3(80), dim3(256), 0, stream>>>(W, a, Wt_bf, wa);
    k_gemm_sp<<<dim3(1152), dim3(256), 0, stream>>>(h, Wt_bf, wa, adj, htT, s1, t1, adjm);
    k_attn<<<dim3(512), dim3(256), 0, stream>>>(htT, s1, t1, adjm, out);
}